// Round 17
// baseline (102.990 us; speedup 1.0000x reference)
//
#include <hip/hip_runtime.h>

#define DIN 512
#define DOUT 512

typedef int v4i __attribute__((ext_vector_type(4)));
typedef float v4f __attribute__((ext_vector_type(4)));

#define WAITLGKM0() asm volatile("s_waitcnt lgkmcnt(0)" ::: "memory")

// exact-divide quantize (weights/bias path, matches ref bit-for-bit)
__device__ __forceinline__ int q8f(float v, float s) {
    int i = (int)rintf(v / s);
    i = i < -128 ? -128 : (i > 127 ? 127 : i);
    return i & 255;
}
// multiply-by-reciprocal quantize (activation path; flip prob ~2^-22, contribution ~0.005 << 0.0525)
__device__ __forceinline__ int q8m(float v, float inv) {
    int i = (int)rintf(v * inv);
    i = i < -128 ? -128 : (i > 127 ? 127 : i);
    return i & 255;
}

// ---------------- Kernel 1: global absmax of x ----------------
__global__ void absmax_kernel(const float4* __restrict__ x4, unsigned* __restrict__ amax, int n4) {
    float m = 0.f;
    int stride = gridDim.x * blockDim.x;
    for (int i = blockIdx.x * blockDim.x + threadIdx.x; i < n4; i += stride) {
        float4 v = x4[i];
        m = fmaxf(m, fmaxf(fmaxf(fabsf(v.x), fabsf(v.y)), fmaxf(fabsf(v.z), fabsf(v.w))));
    }
#pragma unroll
    for (int off = 32; off; off >>= 1) m = fmaxf(m, __shfl_xor(m, off));
    __shared__ float sm[4];
    int lane = threadIdx.x & 63, w = threadIdx.x >> 6;
    if (lane == 0) sm[w] = m;
    __syncthreads();
    if (threadIdx.x == 0) {
        m = fmaxf(fmaxf(sm[0], sm[1]), fmaxf(sm[2], sm[3]));
        atomicMax(amax, __float_as_uint(m));  // positive floats: uint compare == float compare
    }
}

// ---------------- Kernel 2: weight quant -> frag-linear wq8 (+ amax zero-init) ----------------
// wq8 byte(og,ks,kq,r,b) = og*8192 + ks*1024 + kq*256 + r*16 + b ==> a wave's
// A-frag (og,ks) is CONTIGUOUS 1KB at wq8 + og*8192 + ks*1024 + lane*16. (R12-validated)
__global__ void quantw_kernel(const float* __restrict__ w, char* __restrict__ wq8,
                              float* __restrict__ wsc, unsigned* __restrict__ amax) {
    int gid = blockIdx.x * blockDim.x + threadIdx.x;
    if (gid == 0) *amax = 0u;   // zero-init; absmax launches after quantw on same stream
    int row = gid >> 6, lane = gid & 63;
    const float4* r4 = (const float4*)(w + (long)row * DIN);
    float4 a = r4[lane * 2];
    float4 b = r4[lane * 2 + 1];
    float m = fmaxf(fmaxf(fmaxf(fabsf(a.x), fabsf(a.y)), fabsf(a.z)),
                    fmaxf(fmaxf(fabsf(a.w), fabsf(b.x)),
                          fmaxf(fmaxf(fabsf(b.y), fabsf(b.z)), fabsf(b.w))));
#pragma unroll
    for (int off = 32; off; off >>= 1) m = fmaxf(m, __shfl_xor(m, off));
    float s = m / 127.0f;
    int lo = q8f(a.x, s) | (q8f(a.y, s) << 8) | (q8f(a.z, s) << 16) | (q8f(a.w, s) << 24);
    int hi = q8f(b.x, s) | (q8f(b.y, s) << 8) | (q8f(b.z, s) << 16) | (q8f(b.w, s) << 24);
    {
        int og = row >> 4, r = row & 15;
        int ks = lane >> 3, kq = (lane >> 1) & 3, bo = (lane & 1) * 8;
        *(int2*)(wq8 + og * 8192 + ks * 1024 + kq * 256 + r * 16 + bo) = make_int2(lo, hi);
    }
    if (lane == 0) wsc[row] = s;
}

// ---------------- Kernel 3: barrier-free per-wave GEMM + per-wave LDS ostage ----------------
// R16 og-loop verbatim. NEW: stores go to a wave-PRIVATE 16KB LDS tile
// (32 rows x 512B, XOR-swizzled ^((row&7)<<4)); every 8 og the tile is flushed
// with 16 nt-store instructions of 2x512B CONTIGUOUS segments. This replaces
// the 16x64B-segment scattered stores (4x transaction amplification) that
// R13-R16 paid on every og-pair. Wave-local lgkmcnt ordering only - still
// zero barriers after the prologue.
__global__ __launch_bounds__(256, 2) void gemm_kernel(
    const float* __restrict__ x, const char* __restrict__ wq8,
    const float* __restrict__ wsc, const float* __restrict__ bias,
    const unsigned* __restrict__ amax, float* __restrict__ out) {
    __shared__ __align__(16) float bsl[512];
    __shared__ __align__(16) float bql[512];
    __shared__ __align__(16) char ostage[4][16384];   // per-wave 32 rows x 512B
    const int t = threadIdx.x, lane = t & 63, wid = t >> 6;
    const float as = __uint_as_float(*amax) / 127.0f;
    const float inv_as = 1.0f / as;

    // fold quantb: two oc per thread
    {
        float s0 = as * wsc[t];
        bsl[t] = s0;
        bql[t] = rintf(bias[t] / s0) * s0;
        float s1 = as * wsc[t + 256];
        bsl[t + 256] = s1;
        bql[t + 256] = rintf(bias[t + 256] / s1) * s1;
    }
    __syncthreads();   // the only barrier

    const int gw = (gridDim.x - 1 - blockIdx.x) * 4 + wid;   // reverse: x L3 recency
    const long m0 = (long)gw * 32;
    const float* xb = x + (m0 + (lane & 15)) * DIN + (lane >> 4) * 16;
    const char* wg = wq8 + lane * 16;
    const int bo = (lane >> 4) * 4;                      // oc sub-offset
    char* ow = ostage[wid];
    const int wbase = (lane & 15) * 512 + (lane >> 4) * 16;  // pair-write base (row=lane&15)
    const int wsw = (lane & 7) << 4;                         // swizzle: (row&7)<<4
    float* outw = out + m0 * DOUT;
    const int frow = lane >> 5;                          // flush: sub-row 0/1
    const int fcol = (lane & 31) * 16;                   // flush: byte within row

    v4i wfA[8], wfB[8], wfC[8], wfD[8];
#define LDW(DST, G) { _Pragma("unroll") for (int ks = 0; ks < 8; ks++) \
        DST[ks] = *(const v4i*)(wg + (G) * 8192 + ks * 1024); }

    // pre-issue first two w-groups; they land during the long x-phase
    LDW(wfA, 0)
    LDW(wfB, 1)

    // ---- x-phase: 16 batches (mi,ks), 4 float4 each, quantize in-register, depth-3
    v4i xa[2][8];
    float4 xv[4][4];
#define LOADB(B, S) { const float4* p_ = (const float4*)(xb + ((B) >> 3) * (16 * DIN) + ((B) & 7) * 64); \
        xv[S][0] = p_[0]; xv[S][1] = p_[1]; xv[S][2] = p_[2]; xv[S][3] = p_[3]; }
#define PK(v) (q8m((v).x, inv_as) | (q8m((v).y, inv_as) << 8) | \
               (q8m((v).z, inv_as) << 16) | (q8m((v).w, inv_as) << 24))
#define QUANTB(B, S) { v4i q_; \
        q_[0] = PK(xv[S][0]); q_[1] = PK(xv[S][1]); q_[2] = PK(xv[S][2]); q_[3] = PK(xv[S][3]); \
        xa[(B) >> 3][(B) & 7] = q_; }

    LOADB(0, 0)
    LOADB(1, 1)
    LOADB(2, 2)
#pragma unroll
    for (int b = 0; b < 16; b++) {
        if (b + 3 < 16) LOADB(b + 3, (b + 3) & 3)
        QUANTB(b, b & 3)
    }

    // ---- og-loop: 4 og per iteration, 4-buffer w rotation, LDS ostage + flush
#define CCOMP(WF, OG, V0, V1) { \
    v4i a00, a01, a10, a11; \
    const v4i Z = {0, 0, 0, 0}; \
    a00 = __builtin_amdgcn_mfma_i32_16x16x64_i8(WF[0], xa[0][0], Z, 0, 0, 0); \
    a10 = __builtin_amdgcn_mfma_i32_16x16x64_i8(WF[0], xa[1][0], Z, 0, 0, 0); \
    a01 = __builtin_amdgcn_mfma_i32_16x16x64_i8(WF[1], xa[0][1], Z, 0, 0, 0); \
    a11 = __builtin_amdgcn_mfma_i32_16x16x64_i8(WF[1], xa[1][1], Z, 0, 0, 0); \
    _Pragma("unroll") for (int kp = 2; kp < 8; kp += 2) { \
        a00 = __builtin_amdgcn_mfma_i32_16x16x64_i8(WF[kp], xa[0][kp], a00, 0, 0, 0); \
        a10 = __builtin_amdgcn_mfma_i32_16x16x64_i8(WF[kp], xa[1][kp], a10, 0, 0, 0); \
        a01 = __builtin_amdgcn_mfma_i32_16x16x64_i8(WF[kp + 1], xa[0][kp + 1], a01, 0, 0, 0); \
        a11 = __builtin_amdgcn_mfma_i32_16x16x64_i8(WF[kp + 1], xa[1][kp + 1], a11, 0, 0, 0); } \
    v4i s0 = a00 + a01, s1 = a10 + a11; \
    float4 s4 = *(const float4*)&bsl[(OG) * 16 + bo]; \
    float4 q4 = *(const float4*)&bql[(OG) * 16 + bo]; \
    V0[0] = (float)s0[0] * s4.x + q4.x; V0[1] = (float)s0[1] * s4.y + q4.y; \
    V0[2] = (float)s0[2] * s4.z + q4.z; V0[3] = (float)s0[3] * s4.w + q4.w; \
    V1[0] = (float)s1[0] * s4.x + q4.x; V1[1] = (float)s1[1] * s4.y + q4.y; \
    V1[2] = (float)s1[2] * s4.z + q4.z; V1[3] = (float)s1[3] * s4.w + q4.w; }
// write og-pair results into the wave's ostage (rows lane&15 and +16)
#define DSW(OG, V0A, V0B, V1A, V1B) { \
    int q64_ = ((OG) & 7) * 64; \
    *(v4f*)(ow + ((wbase + q64_) ^ wsw)) = V0A; \
    *(v4f*)(ow + ((wbase + q64_ + 64) ^ wsw)) = V0B; \
    *(v4f*)(ow + ((wbase + 8192 + q64_) ^ wsw)) = V1A; \
    *(v4f*)(ow + ((wbase + 8192 + q64_ + 64) ^ wsw)) = V1B; }
// flush 32 rows x 512B: 16 nt stores, each 2 x 512B contiguous segments
#define FLUSH(F) { \
    _Pragma("unroll") for (int s_ = 0; s_ < 16; s_++) { \
        int row_ = 2 * s_ + frow; \
        v4f v_ = *(const v4f*)(ow + ((row_ * 512 + fcol) ^ ((row_ & 7) << 4))); \
        __builtin_nontemporal_store(v_, (v4f*)(outw + row_ * DOUT + (F) * 128 + (lane & 31) * 4)); \
    } \
    WAITLGKM0(); }

#pragma unroll 1
    for (int og = 0; og < 32; og += 4) {
        v4f v0a, v1a, v0b, v1b;
        LDW(wfC, og + 2)
        CCOMP(wfA, og, v0a, v1a)
        LDW(wfD, og + 3)
        CCOMP(wfB, og + 1, v0b, v1b)
        DSW(og, v0a, v0b, v1a, v1b)
        if (og + 4 < 32) LDW(wfA, og + 4)
        CCOMP(wfC, og + 2, v0a, v1a)
        if (og + 5 < 32) LDW(wfB, og + 5)
        CCOMP(wfD, og + 3, v0b, v1b)
        DSW(og + 2, v0a, v0b, v1a, v1b)
        if (og & 4) FLUSH(og >> 3)
    }
#undef LDW
#undef LOADB
#undef PK
#undef QUANTB
#undef CCOMP
#undef DSW
#undef FLUSH
}

extern "C" void kernel_launch(void* const* d_in, const int* in_sizes, int n_in,
                              void* d_out, int out_size, void* d_ws, size_t ws_size,
                              hipStream_t stream) {
    const float* x    = (const float*)d_in[0];
    const float* w    = (const float*)d_in[1];
    const float* bias = (const float*)d_in[2];
    float* out = (float*)d_out;
    const int M = in_sizes[0] / DIN;   // 65536

    char* ws = (char*)d_ws;
    unsigned* amax = (unsigned*)ws;
    char* wq8  = ws + 64;
    float* wsc = (float*)(wq8 + (long)DOUT * DIN);

    quantw_kernel<<<(DOUT * 64) / 256, 256, 0, stream>>>(w, wq8, wsc, amax);
    absmax_kernel<<<2048, 256, 0, stream>>>((const float4*)x, amax, in_sizes[0] / 4);
    gemm_kernel<<<M / 128, 256, 0, stream>>>(x, wq8, wsc, bias, amax, out);
}